// Round 11
// baseline (221.809 us; speedup 1.0000x reference)
//
#include <hip/hip_runtime.h>
#include <hip/hip_bf16.h>

typedef unsigned short u16;
typedef __attribute__((ext_vector_type(8))) short bf16x8;
typedef __attribute__((ext_vector_type(4))) float f32x4;
typedef __attribute__((ext_vector_type(8))) unsigned short u16x8;
typedef __attribute__((ext_vector_type(4))) unsigned int u32x4;

#define MFMA16(a, b, c) __builtin_amdgcn_mfma_f32_16x16x32_bf16((a), (b), (c), 0, 0, 0)

// attn LDS XOR swizzle for 128-byte rows (R4/R6-proven)
#define SWZB(row) ((((row) & 3) | ((((row) >> 3) & 1) << 2)) << 4)

__device__ __forceinline__ u16 f2b(float f) {
  union { float f; unsigned u; } c; c.f = f;
  unsigned u = c.u;
  u += 0x7FFFu + ((u >> 16) & 1u);   // RNE
  return (u16)(u >> 16);
}

__device__ __forceinline__ unsigned cvt_pk_bf16(float a, float b) {
  unsigned r;
  asm("v_cvt_pk_bf16_f32 %0, %1, %2" : "=v"(r) : "v"(a), "v"(b));
  return r;
}

__device__ __forceinline__ void gload_lds16(const u16* g, u16* l) {
  __builtin_amdgcn_global_load_lds(
      (__attribute__((address_space(1))) void*)(g),
      (__attribute__((address_space(3))) void*)(l),
      16, 0, 0);
}

// ---------------- f32 -> bf16 convert (x) ----------------
__global__ __launch_bounds__(256) void convert_f32_bf16(const float* __restrict__ in,
                                                        u16* __restrict__ out) {
  int i = (blockIdx.x * 256 + threadIdx.x) * 8;
  float4 a = *(const float4*)&in[i];
  float4 b = *(const float4*)&in[i + 4];
  u16x8 o;
  o[0] = f2b(a.x); o[1] = f2b(a.y); o[2] = f2b(a.z); o[3] = f2b(a.w);
  o[4] = f2b(b.x); o[5] = f2b(b.y); o[6] = f2b(b.z); o[7] = f2b(b.w);
  *(u16x8*)&out[i] = o;
}

// ---------------- transpose + convert weights: Wt[n][k] = bf16(W[k][n]) ----------------
__global__ __launch_bounds__(256) void transpose_convert_w(
    const float* __restrict__ W0, const float* __restrict__ W1,
    const float* __restrict__ W2, const float* __restrict__ W3,
    u16* __restrict__ Wts) {
  __shared__ float t[32][33];
  int z = blockIdx.z;
  const float* W = (z == 0) ? W0 : (z == 1) ? W1 : (z == 2) ? W2 : W3;
  u16* Wt = Wts + (size_t)z * 1048576;
  int n0 = blockIdx.x * 32, k0 = blockIdx.y * 32;
  int tx = threadIdx.x, ty = threadIdx.y;
#pragma unroll
  for (int i = 0; i < 32; i += 8)
    t[ty + i][tx] = W[(size_t)(k0 + ty + i) * 1024 + n0 + tx];
  __syncthreads();
#pragma unroll
  for (int i = 0; i < 32; i += 8)
    Wt[(size_t)(n0 + ty + i) * 1024 + k0 + tx] = f2b(t[tx][ty + i]);
}

// ---------------- bf16 GEMM: out = A(8192x1024) * W(1024x1024) + bias ----------------
// m97 structure (proven 57us for QKV): 128x128 tile, BK=32, 4 waves 2x2,
// global_load_lds width 16, 16x16x32 MFMA, 4x4 acc per wave.
// z==0 (Q): folds 1/sqrt(DH)*log2(e) (softmax runs in exp2 domain).
// z==2 (V): writes DIRECTLY into per-head-transposed Vt[bh][d][s'] using the
// correct reshape mapping: for out element (row,col):
//   b=row>>11, h=(row>>7)&15, s'=((row&127)<<4)|(col>>6), d=col&63
// (carry-free since (row&127)*16+15 < 2048). Same values as the old
// transpose_v path -> numerics identical.
template <bool F32OUT>
__global__ __launch_bounds__(256) void gemm_kernel(
    const u16* __restrict__ A, const u16* __restrict__ Wt0,
    const float* __restrict__ bias0, const float* __restrict__ bias1,
    const float* __restrict__ bias2,
    u16* __restrict__ outB, u16* __restrict__ Vt, float* __restrict__ outF) {
  int z = blockIdx.z;
  const u16* Wt = Wt0 + (size_t)z * 1048576;
  const float* bias = (z == 0) ? bias0 : (z == 1) ? bias1 : bias2;
  u16* outb = outB + (size_t)z * 8388608;
  float oscale = (!F32OUT && z == 0) ? 0.125f * 1.44269504088896f : 1.0f;

  __shared__ u16 Alds[128 * 32];
  __shared__ u16 Blds[128 * 32];
  int tid = threadIdx.x;
  int lane = tid & 63, w = tid >> 6;
  int brow = blockIdx.x * 128;
  int bcol = blockIdx.y * 128;
  int wr = (w >> 1) * 64, wc = (w & 1) * 64;
  int r = lane & 15, half = lane >> 4;

  f32x4 acc[4][4] = {};
  int f0 = (w * 2 + 0) * 512 + lane * 8;
  int f1 = (w * 2 + 1) * 512 + lane * 8;
  const u16* Abase = A + (size_t)brow * 1024;
  const u16* Bbase = Wt + (size_t)bcol * 1024;

  for (int k0 = 0; k0 < 1024; k0 += 32) {
    gload_lds16(Abase + (size_t)(f0 >> 5) * 1024 + k0 + (f0 & 31), &Alds[(w * 2 + 0) * 512]);
    gload_lds16(Abase + (size_t)(f1 >> 5) * 1024 + k0 + (f1 & 31), &Alds[(w * 2 + 1) * 512]);
    gload_lds16(Bbase + (size_t)(f0 >> 5) * 1024 + k0 + (f0 & 31), &Blds[(w * 2 + 0) * 512]);
    gload_lds16(Bbase + (size_t)(f1 >> 5) * 1024 + k0 + (f1 & 31), &Blds[(w * 2 + 1) * 512]);
    __syncthreads();
    bf16x8 af[4], bf[4];
#pragma unroll
    for (int m = 0; m < 4; ++m)
      af[m] = *(const bf16x8*)&Alds[(wr + m * 16 + r) * 32 + half * 8];
#pragma unroll
    for (int n = 0; n < 4; ++n)
      bf[n] = *(const bf16x8*)&Blds[(wc + n * 16 + r) * 32 + half * 8];
#pragma unroll
    for (int m = 0; m < 4; ++m)
#pragma unroll
      for (int n = 0; n < 4; ++n)
        acc[m][n] = MFMA16(af[m], bf[n], acc[m][n]);
    __syncthreads();
  }
#pragma unroll
  for (int m = 0; m < 4; ++m) {
    int rowb = brow + wr + m * 16 + half * 4;
#pragma unroll
    for (int n = 0; n < 4; ++n) {
      int col = bcol + wc + n * 16 + r;
      float bv = bias[col];
      if (!F32OUT && z == 2) {
        // direct reshape-transposed V write
        const int b = rowb >> 11;
        const int h = (rowb >> 7) & 15;
        const int d = col & 63;
        const int sbase = ((rowb & 127) << 4) | (col >> 6);
        u16* vp = Vt + (size_t)(b * 16 + h) * 131072 + (size_t)d * 2048 + sbase;
#pragma unroll
        for (int j = 0; j < 4; ++j)
          vp[j << 4] = f2b(acc[m][n][j] + bv);
      } else {
#pragma unroll
        for (int j = 0; j < 4; ++j) {
          float v = (acc[m][n][j] + bv) * oscale;
          size_t idx = (size_t)(rowb + j) * 1024 + col;
          if (F32OUT) outF[idx] = v;
          else        outb[idx] = f2b(v);
        }
      }
    }
  }
}

// ---------------- causal flash attention per (b,h): N=2048, D=64 ----------------
// R6-proven inner structure; this round only the per-tile sync changes:
// raw s_barrier(A) -> issue stage(kt+1) -> counted s_waitcnt vmcnt(4) ->
// raw s_barrier(B). Next-tile loads enter the pipe BEFORE waiting on the
// current tile's (T4 issue-before-wait); no full vmcnt(0) drain mid-loop.
// Race-safety: buf[(kt+1)&1]'s last readers (compute(kt-1)) precede barrier A
// in program order for every wave; barrier B publishes all waves' stage(kt).
__device__ __forceinline__ void attn_stage(
    const u16* __restrict__ Kb, const u16* __restrict__ Vtb,
    u16* Kl, u16* Vl, int kb, int tid) {
  const int row0 = tid >> 3;
  const int cb0 = (tid & 7) << 4;
  const int row1 = row0 + 32;
  gload_lds16(Kb + (size_t)(kb + row0) * 64 + ((cb0 ^ SWZB(row0)) >> 1), Kl + tid * 8);
  gload_lds16(Kb + (size_t)(kb + row1) * 64 + ((cb0 ^ SWZB(row1)) >> 1), Kl + 2048 + tid * 8);
  gload_lds16(Vtb + (size_t)row0 * 2048 + kb + ((cb0 ^ SWZB(row0)) >> 1), Vl + tid * 8);
  gload_lds16(Vtb + (size_t)row1 * 2048 + kb + ((cb0 ^ SWZB(row1)) >> 1), Vl + 2048 + tid * 8);
}

__device__ __forceinline__ void attn_strip(
    const u16* __restrict__ Qb, const u16* __restrict__ Kb,
    const u16* __restrict__ Vtb, u16* __restrict__ Zb,
    u16 (*Kl)[4096], u16 (*Vl)[4096], int qrow, int nt, int tid) {
  const int lane = tid & 63;
  const int r = lane & 15, half = lane >> 4;
  const bf16x8 qf0 = *(const bf16x8*)&Qb[(qrow + r) * 64 + half * 8];
  const bf16x8 qf1 = *(const bf16x8*)&Qb[(qrow + r) * 64 + 32 + half * 8];
  const int q = qrow + r;
  f32x4 om[4] = {};
  float m_run = -1e30f, l_run = 0.f;

  __syncthreads();                       // strip boundary: full drain (once)
  attn_stage(Kb, Vtb, Kl[0], Vl[0], 0, tid);
  int cur = 0;

  for (int kt = 0; kt < nt; ++kt) {
    const int kb = kt * 64;
    asm volatile("s_barrier" ::: "memory");              // A: seal buf^1 readers
    if (kt + 1 < nt) {
      attn_stage(Kb, Vtb, Kl[cur ^ 1], Vl[cur ^ 1], kb + 64, tid);
      asm volatile("s_waitcnt vmcnt(4)" ::: "memory");   // own stage(kt) landed
    } else {
      asm volatile("s_waitcnt vmcnt(0)" ::: "memory");
    }
    asm volatile("s_barrier" ::: "memory");              // B: all stage(kt) landed
    const char* Kc = (const char*)Kl[cur];
    const char* Vc = (const char*)Vl[cur];

    f32x4 sT[2][2];
#pragma unroll
    for (int c = 0; c < 2; ++c)
#pragma unroll
      for (int t = 0; t < 2; ++t) {
        const int krow = c * 32 + ((r >> 2) << 3) + t * 4 + (r & 3);
        const char* krp = Kc + krow * 128;
        const bf16x8 kf0 = *(const bf16x8*)(krp + ((half * 16) ^ SWZB(krow)));
        const bf16x8 kf1 = *(const bf16x8*)(krp + ((64 + half * 16) ^ SWZB(krow)));
        f32x4 zc = {};
        zc = MFMA16(kf0, qf0, zc);
        zc = MFMA16(kf1, qf1, zc);
        sT[c][t] = zc;
      }
    if (kt == nt - 1) {
#pragma unroll
      for (int c = 0; c < 2; ++c)
#pragma unroll
        for (int t = 0; t < 2; ++t)
#pragma unroll
          for (int j = 0; j < 4; ++j)
            if (kb + c * 32 + half * 8 + t * 4 + j > q) sT[c][t][j] = -1e30f;
    }
    float mloc;
    {
      float a0 = fmaxf(fmaxf(sT[0][0][0], sT[0][0][1]), fmaxf(sT[0][0][2], sT[0][0][3]));
      float a1 = fmaxf(fmaxf(sT[0][1][0], sT[0][1][1]), fmaxf(sT[0][1][2], sT[0][1][3]));
      float a2 = fmaxf(fmaxf(sT[1][0][0], sT[1][0][1]), fmaxf(sT[1][0][2], sT[1][0][3]));
      float a3 = fmaxf(fmaxf(sT[1][1][0], sT[1][1][1]), fmaxf(sT[1][1][2], sT[1][1][3]));
      mloc = fmaxf(fmaxf(a0, a1), fmaxf(a2, a3));
    }
    if (__any(mloc > m_run + 8.0f)) {
      float mrow = fmaxf(mloc, __shfl_xor(mloc, 16));
      mrow = fmaxf(mrow, __shfl_xor(mrow, 32));
      const float nm = fmaxf(m_run, mrow);
      const float corr = __builtin_exp2f(m_run - nm);
      m_run = nm;
      l_run *= corr;
#pragma unroll
      for (int f = 0; f < 4; ++f)
#pragma unroll
        for (int j = 0; j < 4; ++j) om[f][j] *= corr;
    }
    const float mb = m_run;
    float lloc = 0.f;
    u32x4 pw[2];
#pragma unroll
    for (int c = 0; c < 2; ++c)
#pragma unroll
      for (int t = 0; t < 2; ++t) {
        const float e0 = __builtin_exp2f(sT[c][t][0] - mb);
        const float e1 = __builtin_exp2f(sT[c][t][1] - mb);
        const float e2 = __builtin_exp2f(sT[c][t][2] - mb);
        const float e3 = __builtin_exp2f(sT[c][t][3] - mb);
        lloc += (e0 + e1) + (e2 + e3);
        pw[c][t * 2 + 0] = cvt_pk_bf16(e0, e1);
        pw[c][t * 2 + 1] = cvt_pk_bf16(e2, e3);
      }
    l_run += lloc;
#pragma unroll
    for (int c = 0; c < 2; ++c) {
      const bf16x8 pb = __builtin_bit_cast(bf16x8, pw[c]);
#pragma unroll
      for (int f = 0; f < 4; ++f) {
        const int vrow = f * 16 + r;
        const bf16x8 vf = *(const bf16x8*)(Vc + vrow * 128 + ((c * 64 + half * 16) ^ SWZB(vrow)));
        om[f] = MFMA16(vf, pb, om[f]);
      }
    }
    cur ^= 1;
  }
  float lt = l_run;
  lt += __shfl_xor(lt, 16);
  lt += __shfl_xor(lt, 32);
  const float inv = 1.0f / lt;
#pragma unroll
  for (int f = 0; f < 4; ++f) {
    ushort4 st;
    st.x = f2b(om[f][0] * inv);
    st.y = f2b(om[f][1] * inv);
    st.z = f2b(om[f][2] * inv);
    st.w = f2b(om[f][3] * inv);
    *(ushort4*)&Zb[(size_t)q * 64 + f * 16 + half * 4] = st;
  }
}

__global__ __launch_bounds__(256) void attn_kernel(
    const u16* __restrict__ Q, const u16* __restrict__ K,
    const u16* __restrict__ Vt, u16* __restrict__ Z) {
  __shared__ u16 Kl[2][4096];
  __shared__ u16 Vl[2][4096];
  // XCD-affinity: all q-block-pairs of a head on one XCD (HW round-robin L%8)
  const int L = blockIdx.x;
  const int xcd = L & 7;
  const int i = L >> 3;
  const int bh = ((i >> 4) << 3) | xcd;
  const int x = i & 15;
  const int tid = threadIdx.x;
  const int w = tid >> 6;
  const u16* Qb = Q + (size_t)bh * 131072;
  const u16* Kb = K + (size_t)bh * 131072;
  const u16* Vb = Vt + (size_t)bh * 131072;
  u16* Zb = Z + (size_t)bh * 131072;
  attn_strip(Qb, Kb, Vb, Zb, Kl, Vl, x * 64 + w * 16, x + 1, tid);
  attn_strip(Qb, Kb, Vb, Zb, Kl, Vl, (31 - x) * 64 + w * 16, 32 - x, tid);
}

extern "C" void kernel_launch(void* const* d_in, const int* in_sizes, int n_in,
                              void* d_out, int out_size, void* d_ws, size_t ws_size,
                              hipStream_t stream) {
  (void)in_sizes; (void)n_in; (void)out_size; (void)ws_size;
  const float* x  = (const float*)d_in[0];
  const float* Wq = (const float*)d_in[1];
  const float* bq = (const float*)d_in[2];
  const float* Wk = (const float*)d_in[3];
  const float* bk = (const float*)d_in[4];
  const float* Wv = (const float*)d_in[5];
  const float* bv = (const float*)d_in[6];
  const float* Wo = (const float*)d_in[7];
  const float* bo = (const float*)d_in[8];
  float* out = (float*)d_out;

  char* ws = (char*)d_ws;
  u16* xb  = (u16*)(ws);                  // 16 MB, reused as Z after attention
  u16* Wts = (u16*)(ws + 16777216);       // 4 x 2 MB (q,k,v,o; n-major bf16)
  u16* Qb  = (u16*)(ws + 25165824);       // 16 MB
  u16* Kb  = (u16*)(ws + 41943040);       // 16 MB  (= Qb + 8388608 u16)
  u16* Vtb = (u16*)(ws + 58720256);       // 16 MB  (total 72 MB)

  convert_f32_bf16<<<4096, 256, 0, stream>>>(x, xb);
  {
    dim3 g(32, 32, 4), b(32, 8);
    transpose_convert_w<<<g, b, 0, stream>>>(Wq, Wk, Wv, Wo, Wts);
  }
  {
    dim3 g(64, 8, 3), b(256);
    gemm_kernel<false><<<g, b, 0, stream>>>(xb, Wts, bq, bk, bv, Qb, Vtb, nullptr);
  }
  {
    dim3 g(1024), b(256);
    attn_kernel<<<g, b, 0, stream>>>(Qb, Kb, Vtb, xb /* Z */);
  }
  {
    dim3 g(64, 8, 1), b(256);
    gemm_kernel<true><<<g, b, 0, stream>>>(xb, Wts + 3 * 1048576, bo, bo, bo, Qb, Vtb, out);
  }
}

// Round 12
// 188.961 us; speedup vs baseline: 1.1738x; 1.1738x over previous
//
#include <hip/hip_runtime.h>
#include <hip/hip_bf16.h>

typedef unsigned short u16;
typedef __attribute__((ext_vector_type(8))) short bf16x8;
typedef __attribute__((ext_vector_type(4))) float f32x4;
typedef __attribute__((ext_vector_type(8))) unsigned short u16x8;
typedef __attribute__((ext_vector_type(4))) unsigned int u32x4;

#define MFMA16(a, b, c) __builtin_amdgcn_mfma_f32_16x16x32_bf16((a), (b), (c), 0, 0, 0)

// attn LDS XOR swizzle for 128-byte rows (R4/R6-proven)
#define SWZB(row) ((((row) & 3) | ((((row) >> 3) & 1) << 2)) << 4)

__device__ __forceinline__ u16 f2b(float f) {
  union { float f; unsigned u; } c; c.f = f;
  unsigned u = c.u;
  u += 0x7FFFu + ((u >> 16) & 1u);   // RNE
  return (u16)(u >> 16);
}

__device__ __forceinline__ unsigned cvt_pk_bf16(float a, float b) {
  unsigned r;
  asm("v_cvt_pk_bf16_f32 %0, %1, %2" : "=v"(r) : "v"(a), "v"(b));
  return r;
}

__device__ __forceinline__ void gload_lds16(const u16* g, u16* l) {
  __builtin_amdgcn_global_load_lds(
      (__attribute__((address_space(1))) void*)(g),
      (__attribute__((address_space(3))) void*)(l),
      16, 0, 0);
}

// ---------------- f32 -> bf16 convert (x) ----------------
__global__ __launch_bounds__(256) void convert_f32_bf16(const float* __restrict__ in,
                                                        u16* __restrict__ out) {
  int i = (blockIdx.x * 256 + threadIdx.x) * 8;
  float4 a = *(const float4*)&in[i];
  float4 b = *(const float4*)&in[i + 4];
  u16x8 o;
  o[0] = f2b(a.x); o[1] = f2b(a.y); o[2] = f2b(a.z); o[3] = f2b(a.w);
  o[4] = f2b(b.x); o[5] = f2b(b.y); o[6] = f2b(b.z); o[7] = f2b(b.w);
  *(u16x8*)&out[i] = o;
}

// ---------------- transpose + convert weights: Wt[n][k] = bf16(W[k][n]) ----------------
__global__ __launch_bounds__(256) void transpose_convert_w(
    const float* __restrict__ W0, const float* __restrict__ W1,
    const float* __restrict__ W2, const float* __restrict__ W3,
    u16* __restrict__ Wts) {
  __shared__ float t[32][33];
  int z = blockIdx.z;
  const float* W = (z == 0) ? W0 : (z == 1) ? W1 : (z == 2) ? W2 : W3;
  u16* Wt = Wts + (size_t)z * 1048576;
  int n0 = blockIdx.x * 32, k0 = blockIdx.y * 32;
  int tx = threadIdx.x, ty = threadIdx.y;
#pragma unroll
  for (int i = 0; i < 32; i += 8)
    t[ty + i][tx] = W[(size_t)(k0 + ty + i) * 1024 + n0 + tx];
  __syncthreads();
#pragma unroll
  for (int i = 0; i < 32; i += 8)
    Wt[(size_t)(n0 + ty + i) * 1024 + k0 + tx] = f2b(t[tx][ty + i]);
}

// ---------------- per-(b,h) V transpose: Vt[d][s] = V[s][d] ----------------
// LDS-staged (coalesced both sides) — the R4-proven path; direct-scatter
// epilogue in the GEMM was a 2x GEMM regression (R11: 4KB-stride u16 stores).
__global__ __launch_bounds__(256) void transpose_v(const u16* __restrict__ V,
                                                   u16* __restrict__ Vt) {
  __shared__ u16 t[32][33];
  int bh = blockIdx.z;
  int s0 = blockIdx.x * 32, d0 = blockIdx.y * 32;
  const u16* Vb = V + (size_t)bh * 131072;
  u16* Vtb = Vt + (size_t)bh * 131072;
  int tx = threadIdx.x, ty = threadIdx.y;
#pragma unroll
  for (int i = 0; i < 32; i += 8)
    t[ty + i][tx] = Vb[(s0 + ty + i) * 64 + d0 + tx];
  __syncthreads();
#pragma unroll
  for (int i = 0; i < 32; i += 8)
    Vtb[(d0 + ty + i) * 2048 + s0 + tx] = t[tx][ty + i];
}

// ---------------- bf16 GEMM: out = A(8192x1024) * W(1024x1024) + bias ----------------
// m97 structure (R4-proven): 128x128 tile, BK=32, 4 waves 2x2,
// global_load_lds width 16, 16x16x32 MFMA, 4x4 acc per wave.
// z==0 (Q): folds 1/sqrt(DH)*log2(e) (softmax runs in exp2 domain).
template <bool F32OUT>
__global__ __launch_bounds__(256) void gemm_kernel(
    const u16* __restrict__ A, const u16* __restrict__ Wt0,
    const float* __restrict__ bias0, const float* __restrict__ bias1,
    const float* __restrict__ bias2,
    u16* __restrict__ outB, float* __restrict__ outF) {
  int z = blockIdx.z;
  const u16* Wt = Wt0 + (size_t)z * 1048576;
  const float* bias = (z == 0) ? bias0 : (z == 1) ? bias1 : bias2;
  u16* outb = outB + (size_t)z * 8388608;
  float oscale = (!F32OUT && z == 0) ? 0.125f * 1.44269504088896f : 1.0f;

  __shared__ u16 Alds[128 * 32];
  __shared__ u16 Blds[128 * 32];
  int tid = threadIdx.x;
  int lane = tid & 63, w = tid >> 6;
  int brow = blockIdx.x * 128;
  int bcol = blockIdx.y * 128;
  int wr = (w >> 1) * 64, wc = (w & 1) * 64;
  int r = lane & 15, half = lane >> 4;

  f32x4 acc[4][4] = {};
  int f0 = (w * 2 + 0) * 512 + lane * 8;
  int f1 = (w * 2 + 1) * 512 + lane * 8;
  const u16* Abase = A + (size_t)brow * 1024;
  const u16* Bbase = Wt + (size_t)bcol * 1024;

  for (int k0 = 0; k0 < 1024; k0 += 32) {
    gload_lds16(Abase + (size_t)(f0 >> 5) * 1024 + k0 + (f0 & 31), &Alds[(w * 2 + 0) * 512]);
    gload_lds16(Abase + (size_t)(f1 >> 5) * 1024 + k0 + (f1 & 31), &Alds[(w * 2 + 1) * 512]);
    gload_lds16(Bbase + (size_t)(f0 >> 5) * 1024 + k0 + (f0 & 31), &Blds[(w * 2 + 0) * 512]);
    gload_lds16(Bbase + (size_t)(f1 >> 5) * 1024 + k0 + (f1 & 31), &Blds[(w * 2 + 1) * 512]);
    __syncthreads();
    bf16x8 af[4], bf[4];
#pragma unroll
    for (int m = 0; m < 4; ++m)
      af[m] = *(const bf16x8*)&Alds[(wr + m * 16 + r) * 32 + half * 8];
#pragma unroll
    for (int n = 0; n < 4; ++n)
      bf[n] = *(const bf16x8*)&Blds[(wc + n * 16 + r) * 32 + half * 8];
#pragma unroll
    for (int m = 0; m < 4; ++m)
#pragma unroll
      for (int n = 0; n < 4; ++n)
        acc[m][n] = MFMA16(af[m], bf[n], acc[m][n]);
    __syncthreads();
  }
#pragma unroll
  for (int m = 0; m < 4; ++m) {
    int rowb = brow + wr + m * 16 + half * 4;
#pragma unroll
    for (int n = 0; n < 4; ++n) {
      int col = bcol + wc + n * 16 + r;
      float bv = bias[col];
#pragma unroll
      for (int j = 0; j < 4; ++j) {
        float v = (acc[m][n][j] + bv) * oscale;
        size_t idx = (size_t)(rowb + j) * 1024 + col;
        if (F32OUT) outF[idx] = v;
        else        outb[idx] = f2b(v);
      }
    }
  }
}

// ---------------- causal flash attention per (b,h): N=2048, D=64 ----------------
// R6-proven inner structure with the T4 issue-before-wait sync (kept from R11,
// absmax-verified): raw s_barrier(A) -> issue stage(kt+1) -> counted
// s_waitcnt vmcnt(4) -> raw s_barrier(B). No vmcnt(0) drain mid-loop.
__device__ __forceinline__ void attn_stage(
    const u16* __restrict__ Kb, const u16* __restrict__ Vtb,
    u16* Kl, u16* Vl, int kb, int tid) {
  const int row0 = tid >> 3;
  const int cb0 = (tid & 7) << 4;
  const int row1 = row0 + 32;
  gload_lds16(Kb + (size_t)(kb + row0) * 64 + ((cb0 ^ SWZB(row0)) >> 1), Kl + tid * 8);
  gload_lds16(Kb + (size_t)(kb + row1) * 64 + ((cb0 ^ SWZB(row1)) >> 1), Kl + 2048 + tid * 8);
  gload_lds16(Vtb + (size_t)row0 * 2048 + kb + ((cb0 ^ SWZB(row0)) >> 1), Vl + tid * 8);
  gload_lds16(Vtb + (size_t)row1 * 2048 + kb + ((cb0 ^ SWZB(row1)) >> 1), Vl + 2048 + tid * 8);
}

__device__ __forceinline__ void attn_strip(
    const u16* __restrict__ Qb, const u16* __restrict__ Kb,
    const u16* __restrict__ Vtb, u16* __restrict__ Zb,
    u16 (*Kl)[4096], u16 (*Vl)[4096], int qrow, int nt, int tid) {
  const int lane = tid & 63;
  const int r = lane & 15, half = lane >> 4;
  const bf16x8 qf0 = *(const bf16x8*)&Qb[(qrow + r) * 64 + half * 8];
  const bf16x8 qf1 = *(const bf16x8*)&Qb[(qrow + r) * 64 + 32 + half * 8];
  const int q = qrow + r;
  f32x4 om[4] = {};
  float m_run = -1e30f, l_run = 0.f;

  __syncthreads();                       // strip boundary: full drain (once)
  attn_stage(Kb, Vtb, Kl[0], Vl[0], 0, tid);
  int cur = 0;

  for (int kt = 0; kt < nt; ++kt) {
    const int kb = kt * 64;
    asm volatile("s_barrier" ::: "memory");              // A: seal buf^1 readers
    if (kt + 1 < nt) {
      attn_stage(Kb, Vtb, Kl[cur ^ 1], Vl[cur ^ 1], kb + 64, tid);
      asm volatile("s_waitcnt vmcnt(4)" ::: "memory");   // own stage(kt) landed
    } else {
      asm volatile("s_waitcnt vmcnt(0)" ::: "memory");
    }
    asm volatile("s_barrier" ::: "memory");              // B: all stage(kt) landed
    const char* Kc = (const char*)Kl[cur];
    const char* Vc = (const char*)Vl[cur];

    f32x4 sT[2][2];
#pragma unroll
    for (int c = 0; c < 2; ++c)
#pragma unroll
      for (int t = 0; t < 2; ++t) {
        const int krow = c * 32 + ((r >> 2) << 3) + t * 4 + (r & 3);
        const char* krp = Kc + krow * 128;
        const bf16x8 kf0 = *(const bf16x8*)(krp + ((half * 16) ^ SWZB(krow)));
        const bf16x8 kf1 = *(const bf16x8*)(krp + ((64 + half * 16) ^ SWZB(krow)));
        f32x4 zc = {};
        zc = MFMA16(kf0, qf0, zc);
        zc = MFMA16(kf1, qf1, zc);
        sT[c][t] = zc;
      }
    if (kt == nt - 1) {
#pragma unroll
      for (int c = 0; c < 2; ++c)
#pragma unroll
        for (int t = 0; t < 2; ++t)
#pragma unroll
          for (int j = 0; j < 4; ++j)
            if (kb + c * 32 + half * 8 + t * 4 + j > q) sT[c][t][j] = -1e30f;
    }
    float mloc;
    {
      float a0 = fmaxf(fmaxf(sT[0][0][0], sT[0][0][1]), fmaxf(sT[0][0][2], sT[0][0][3]));
      float a1 = fmaxf(fmaxf(sT[0][1][0], sT[0][1][1]), fmaxf(sT[0][1][2], sT[0][1][3]));
      float a2 = fmaxf(fmaxf(sT[1][0][0], sT[1][0][1]), fmaxf(sT[1][0][2], sT[1][0][3]));
      float a3 = fmaxf(fmaxf(sT[1][1][0], sT[1][1][1]), fmaxf(sT[1][1][2], sT[1][1][3]));
      mloc = fmaxf(fmaxf(a0, a1), fmaxf(a2, a3));
    }
    if (__any(mloc > m_run + 8.0f)) {
      float mrow = fmaxf(mloc, __shfl_xor(mloc, 16));
      mrow = fmaxf(mrow, __shfl_xor(mrow, 32));
      const float nm = fmaxf(m_run, mrow);
      const float corr = __builtin_exp2f(m_run - nm);
      m_run = nm;
      l_run *= corr;
#pragma unroll
      for (int f = 0; f < 4; ++f)
#pragma unroll
        for (int j = 0; j < 4; ++j) om[f][j] *= corr;
    }
    const float mb = m_run;
    float lloc = 0.f;
    u32x4 pw[2];
#pragma unroll
    for (int c = 0; c < 2; ++c)
#pragma unroll
      for (int t = 0; t < 2; ++t) {
        const float e0 = __builtin_exp2f(sT[c][t][0] - mb);
        const float e1 = __builtin_exp2f(sT[c][t][1] - mb);
        const float e2 = __builtin_exp2f(sT[c][t][2] - mb);
        const float e3 = __builtin_exp2f(sT[c][t][3] - mb);
        lloc += (e0 + e1) + (e2 + e3);
        pw[c][t * 2 + 0] = cvt_pk_bf16(e0, e1);
        pw[c][t * 2 + 1] = cvt_pk_bf16(e2, e3);
      }
    l_run += lloc;
#pragma unroll
    for (int c = 0; c < 2; ++c) {
      const bf16x8 pb = __builtin_bit_cast(bf16x8, pw[c]);
#pragma unroll
      for (int f = 0; f < 4; ++f) {
        const int vrow = f * 16 + r;
        const bf16x8 vf = *(const bf16x8*)(Vc + vrow * 128 + ((c * 64 + half * 16) ^ SWZB(vrow)));
        om[f] = MFMA16(vf, pb, om[f]);
      }
    }
    cur ^= 1;
  }
  float lt = l_run;
  lt += __shfl_xor(lt, 16);
  lt += __shfl_xor(lt, 32);
  const float inv = 1.0f / lt;
#pragma unroll
  for (int f = 0; f < 4; ++f) {
    ushort4 st;
    st.x = f2b(om[f][0] * inv);
    st.y = f2b(om[f][1] * inv);
    st.z = f2b(om[f][2] * inv);
    st.w = f2b(om[f][3] * inv);
    *(ushort4*)&Zb[(size_t)q * 64 + f * 16 + half * 4] = st;
  }
}

__global__ __launch_bounds__(256) void attn_kernel(
    const u16* __restrict__ Q, const u16* __restrict__ K,
    const u16* __restrict__ Vt, u16* __restrict__ Z) {
  __shared__ u16 Kl[2][4096];
  __shared__ u16 Vl[2][4096];
  // XCD-affinity: all q-block-pairs of a head on one XCD (HW round-robin L%8)
  const int L = blockIdx.x;
  const int xcd = L & 7;
  const int i = L >> 3;
  const int bh = ((i >> 4) << 3) | xcd;
  const int x = i & 15;
  const int tid = threadIdx.x;
  const int w = tid >> 6;
  const u16* Qb = Q + (size_t)bh * 131072;
  const u16* Kb = K + (size_t)bh * 131072;
  const u16* Vb = Vt + (size_t)bh * 131072;
  u16* Zb = Z + (size_t)bh * 131072;
  attn_strip(Qb, Kb, Vb, Zb, Kl, Vl, x * 64 + w * 16, x + 1, tid);
  attn_strip(Qb, Kb, Vb, Zb, Kl, Vl, (31 - x) * 64 + w * 16, 32 - x, tid);
}

extern "C" void kernel_launch(void* const* d_in, const int* in_sizes, int n_in,
                              void* d_out, int out_size, void* d_ws, size_t ws_size,
                              hipStream_t stream) {
  (void)in_sizes; (void)n_in; (void)out_size; (void)ws_size;
  const float* x  = (const float*)d_in[0];
  const float* Wq = (const float*)d_in[1];
  const float* bq = (const float*)d_in[2];
  const float* Wk = (const float*)d_in[3];
  const float* bk = (const float*)d_in[4];
  const float* Wv = (const float*)d_in[5];
  const float* bv = (const float*)d_in[6];
  const float* Wo = (const float*)d_in[7];
  const float* bo = (const float*)d_in[8];
  float* out = (float*)d_out;

  char* ws = (char*)d_ws;
  u16* xb  = (u16*)(ws);                  // 16 MB, reused as Z after attention
  u16* Wts = (u16*)(ws + 16777216);       // 4 x 2 MB (q,k,v,o; n-major bf16)
  u16* Qb  = (u16*)(ws + 25165824);       // 16 MB
  u16* Kb  = (u16*)(ws + 41943040);       // 16 MB
  u16* Vb  = (u16*)(ws + 58720256);       // 16 MB
  u16* Vtb = (u16*)(ws + 75497472);       // 16 MB  (total 92 MB)

  convert_f32_bf16<<<4096, 256, 0, stream>>>(x, xb);
  {
    dim3 g(32, 32, 4), b(32, 8);
    transpose_convert_w<<<g, b, 0, stream>>>(Wq, Wk, Wv, Wo, Wts);
  }
  {
    dim3 g(64, 8, 3), b(256);
    gemm_kernel<false><<<g, b, 0, stream>>>(xb, Wts, bq, bk, bv, Qb, nullptr);
  }
  {
    dim3 g(64, 2, 64), b(32, 8);
    transpose_v<<<g, b, 0, stream>>>(Vb, Vtb);
  }
  {
    dim3 g(1024), b(256);
    attn_kernel<<<g, b, 0, stream>>>(Qb, Kb, Vtb, xb /* Z */);
  }
  {
    dim3 g(64, 8, 1), b(256);
    gemm_kernel<true><<<g, b, 0, stream>>>(xb, Wts + 3 * 1048576, bo, bo, bo, Qb, out);
  }
}